// Round 2
// baseline (587.037 us; speedup 1.0000x reference)
//
#include <hip/hip_runtime.h>
#include <hip/hip_cooperative_groups.h>
#include <hip/hip_bf16.h>
#include <hip/hip_fp16.h>

namespace cg = cooperative_groups;

#define IN_CH 128
#define OUT_CH 64
#define NB 512   // edge-chunk blocks for histo/bucket_scatter phases
#define CB 1024  // compute coop grid: 4 blocks/CU * 256 CUs

typedef _Float16 hh2 __attribute__((ext_vector_type(2)));   // native half2 for v_dot2

// ============================================================================
// Fused preprocessing: histo -> scan -> scatter -> sort  (3 grid syncs)
// 512 blocks x 512 threads; 2 blocks/CU guaranteed (4KB LDS, <=128 VGPR).
// ============================================================================
__global__ void __launch_bounds__(512, 4) pre_kernel(
    const int* __restrict__ row, const int* __restrict__ col,
    int* __restrict__ blkcnt, int* __restrict__ totals,
    unsigned int* __restrict__ tmp, int* __restrict__ off,
    float* __restrict__ dis, unsigned short* __restrict__ eidx,
    int E, int n, int chunk, int nbkt)
{
    __shared__ int sm[1024];
    cg::grid_group grid = cg::this_grid();
    int blk = blockIdx.x, tid = threadIdx.x;

    // ---- phase 1: per-block 256-bucket histogram of col>>8 ----
    if (tid < 256) sm[tid] = 0;
    __syncthreads();
    {
        int s = blk * chunk, e = min(s + chunk, E);
        for (int i = s + tid; i < e; i += 512)
            atomicAdd(&sm[col[i] >> 8], 1);          // LDS atomic
    }
    __syncthreads();
    if (tid < 256) blkcnt[blk * 256 + tid] = sm[tid];
    grid.sync();

    // ---- phase 2: per-bucket exclusive scan over NB block-counts (in place) ----
    if (blk < nbkt) {
        int i0 = 0, i1 = 0, a0 = 0, a1 = 0, lsum = 0;
        if (tid < 256) {
            i0 = (2 * tid) * 256 + blk; i1 = (2 * tid + 1) * 256 + blk;
            a0 = blkcnt[i0]; a1 = blkcnt[i1];
            lsum = a0 + a1;
            sm[tid] = lsum;
        }
        __syncthreads();
        for (int d = 1; d < 256; d <<= 1) {
            int t = 0;
            if (tid < 256 && tid >= d) t = sm[tid - d];
            __syncthreads();
            if (tid < 256 && tid >= d) sm[tid] += t;
            __syncthreads();
        }
        if (tid < 256) {
            int excl = sm[tid] - lsum;
            blkcnt[i0] = excl;
            blkcnt[i1] = excl + a0;
            if (tid == 255) totals[blk] = excl + lsum;
        }
    }
    grid.sync();

    // ---- phase 3: scatter edges into bucket-contiguous tmp ----
    {
        int* ps = sm; int* cur = sm + 256;
        int v = 0;
        if (tid < 256) { v = (tid < nbkt) ? totals[tid] : 0; ps[tid] = v; }
        __syncthreads();
        for (int d = 1; d < 256; d <<= 1) {
            int t = 0;
            if (tid < 256 && tid >= d) t = ps[tid - d];
            __syncthreads();
            if (tid < 256 && tid >= d) ps[tid] += t;
            __syncthreads();
        }
        if (tid < 256) cur[tid] = (ps[tid] - v) + blkcnt[blk * 256 + tid];
        __syncthreads();
        int s = blk * chunk, e = min(s + chunk, E);
        for (int i = s + tid; i < e; i += 512) {
            int c = col[i], r = row[i];
            int p = atomicAdd(&cur[c >> 8], 1);      // LDS atomic
            tmp[p] = ((unsigned)(c & 255) << 16) | (unsigned)r;
        }
    }
    grid.sync();

    // ---- phase 4: per-bucket counting sort -> off/dis/eidx ----
    if (blk < nbkt) {
        int* bs = sm; int* cntl = sm + 256; int* sc = sm + 512; int* posl = sm + 768;
        int v = 0;
        if (tid < 256) { v = (tid < nbkt) ? totals[tid] : 0; bs[tid] = v; }
        __syncthreads();
        for (int d = 1; d < 256; d <<= 1) {
            int t = 0;
            if (tid < 256 && tid >= d) t = bs[tid - d];
            __syncthreads();
            if (tid < 256 && tid >= d) bs[tid] += t;
            __syncthreads();
        }
        if (tid < 256) bs[tid] -= v;                 // exclusive bucket bases
        if (tid < 256) cntl[tid] = 0;
        __syncthreads();
        int s = bs[blk];
        int e = s + totals[blk];
        for (int i = s + tid; i < e; i += 512)
            atomicAdd(&cntl[tmp[i] >> 16], 1);       // LDS atomic
        __syncthreads();
        int c = 0;
        if (tid < 256) { c = cntl[tid]; sc[tid] = c; }
        __syncthreads();
        for (int d = 1; d < 256; d <<= 1) {
            int t = 0;
            if (tid < 256 && tid >= d) t = sc[tid - d];
            __syncthreads();
            if (tid < 256 && tid >= d) sc[tid] += t;
            __syncthreads();
        }
        if (tid < 256) {
            int excl = sc[tid] - c;
            int gid = (blk << 8) + tid;
            if (gid < n) {
                off[gid] = s + excl;
                dis[gid] = rsqrtf((float)(c + 1));   // +1 self-loop (gcn_norm)
            }
            posl[tid] = s + excl;                    // absolute running cursor
        }
        if (blk == 0 && tid == 0) off[n] = E;
        __syncthreads();
        for (int i = s + tid; i < e; i += 512) {
            unsigned int w = tmp[i];
            int p = atomicAdd(&posl[w >> 16], 1);
            eidx[p] = (unsigned short)(w & 0xFFFFu);
        }
    }
}

// ============================================================================
// hop body (unchanged math): t[v] = zin[v] + sum_edges zin[src]; 32-in-flight
// MODE 0: out(half) = dis^2 * t;   MODE 1: out(float) = dis * t + bias
// ============================================================================
#define ACC8(raw) { const __half2* h2_ = (const __half2*)&(raw);              \
    float2 f0_ = __half22float2(h2_[0]), f1_ = __half22float2(h2_[1]);        \
    float2 f2_ = __half22float2(h2_[2]), f3_ = __half22float2(h2_[3]);        \
    a0 += f0_.x; a1 += f0_.y; a2 += f1_.x; a3 += f1_.y;                       \
    a4 += f2_.x; a5 += f2_.y; a6 += f3_.x; a7 += f3_.y; }

template <int MODE>
__device__ __forceinline__ void hop_node(int v, int lane,
                                         const __half* __restrict__ zin,
                                         void* __restrict__ out,
                                         const unsigned short* __restrict__ eidx,
                                         const int* __restrict__ off,
                                         const float* __restrict__ dis,
                                         const float* __restrict__ bias)
{
    int grp = lane >> 3;       // edge slot in the octet
    int sub = lane & 7;        // 16B chunk of the 128B row
    int s = off[v], e = off[v + 1];
    float dv = dis[v];
    float a0 = 0.f, a1 = 0.f, a2 = 0.f, a3 = 0.f;
    float a4 = 0.f, a5 = 0.f, a6 = 0.f, a7 = 0.f;
    if (grp == 0) {            // self-loop term (z already carries dis scaling)
        float4 raw = ((const float4*)(zin + (size_t)v * OUT_CH))[sub];
        ACC8(raw);
    }
    // ---- 32 edges in flight: 4 independent predicated batches ----
    int i0 = s + grp;
    int i1 = i0 + 8, i2 = i0 + 16, i3 = i0 + 24;
    bool h0 = i0 < e, h1 = i1 < e, h2 = i2 < e, h3 = i3 < e;
    int r0 = h0 ? (int)eidx[i0] : 0;
    int r1 = h1 ? (int)eidx[i1] : 0;
    int r2 = h2 ? (int)eidx[i2] : 0;
    int r3 = h3 ? (int)eidx[i3] : 0;
    float4 rA = make_float4(0.f, 0.f, 0.f, 0.f);
    float4 rB = make_float4(0.f, 0.f, 0.f, 0.f);
    float4 rC = make_float4(0.f, 0.f, 0.f, 0.f);
    float4 rD = make_float4(0.f, 0.f, 0.f, 0.f);
    if (h0) rA = ((const float4*)(zin + (size_t)r0 * OUT_CH))[sub];
    if (h1) rB = ((const float4*)(zin + (size_t)r1 * OUT_CH))[sub];
    if (h2) rC = ((const float4*)(zin + (size_t)r2 * OUT_CH))[sub];
    if (h3) rD = ((const float4*)(zin + (size_t)r3 * OUT_CH))[sub];
    ACC8(rA); ACC8(rB); ACC8(rC); ACC8(rD);
    if (e - s > 32) {          // rare (deg > 32): pipelined 2-batch loop
        int j0 = s + 32 + grp, j1 = j0 + 8;
        bool g0 = j0 < e, g1 = j1 < e;
        int q0 = g0 ? (int)eidx[j0] : 0;
        int q1 = g1 ? (int)eidx[j1] : 0;
        while (g0) {           // g1 implies g0
            int k0 = j0 + 16, k1 = j1 + 16;
            bool f0 = k0 < e, f1 = k1 < e;
            int p0 = f0 ? (int)eidx[k0] : 0;
            int p1 = f1 ? (int)eidx[k1] : 0;
            float4 xA = make_float4(0.f, 0.f, 0.f, 0.f);
            float4 xB = make_float4(0.f, 0.f, 0.f, 0.f);
            if (g0) xA = ((const float4*)(zin + (size_t)q0 * OUT_CH))[sub];
            if (g1) xB = ((const float4*)(zin + (size_t)q1 * OUT_CH))[sub];
            ACC8(xA); ACC8(xB);
            j0 = k0; j1 = k1; q0 = p0; q1 = p1; g0 = f0; g1 = f1;
        }
    }
    // reduce the 8 edge slots (lanes differing in bits 3..5)
#pragma unroll
    for (int m = 8; m <= 32; m <<= 1) {
        a0 += __shfl_xor(a0, m, 64); a1 += __shfl_xor(a1, m, 64);
        a2 += __shfl_xor(a2, m, 64); a3 += __shfl_xor(a3, m, 64);
        a4 += __shfl_xor(a4, m, 64); a5 += __shfl_xor(a5, m, 64);
        a6 += __shfl_xor(a6, m, 64); a7 += __shfl_xor(a7, m, 64);
    }
    if (grp == 0) {
        if (MODE == 0) {
            float sc = dv * dv;
            union { __half2 h[4]; float4 f; } u;
            u.h[0] = __floats2half2_rn(sc * a0, sc * a1);
            u.h[1] = __floats2half2_rn(sc * a2, sc * a3);
            u.h[2] = __floats2half2_rn(sc * a4, sc * a5);
            u.h[3] = __floats2half2_rn(sc * a6, sc * a7);
            ((float4*)((__half*)out + (size_t)v * OUT_CH))[sub] = u.f;
        } else {
            const float4* bp = (const float4*)(bias + sub * 8);
            float4 b0 = bp[0], b1 = bp[1];
            float* op = (float*)out + (size_t)v * OUT_CH + sub * 8;
            *(float4*)op = make_float4(fmaf(dv, a0, b0.x), fmaf(dv, a1, b0.y),
                                       fmaf(dv, a2, b0.z), fmaf(dv, a3, b0.w));
            *(float4*)(op + 4) = make_float4(fmaf(dv, a4, b1.x), fmaf(dv, a5, b1.y),
                                             fmaf(dv, a6, b1.z), fmaf(dv, a7, b1.w));
        }
    }
}

// ============================================================================
// Fused compute: gemm -> hop0 -> hop1  (2 grid syncs)
// 1024 blocks x 256 threads; 4 blocks/CU guaranteed (33.8KB LDS, <=128 VGPR).
// ============================================================================
__global__ void __launch_bounds__(256, 4) compute_kernel(
    const float* __restrict__ x, const float* __restrict__ W,
    const float* __restrict__ dis, const float* __restrict__ bias,
    __half* __restrict__ zA, __half* __restrict__ zB,
    float* __restrict__ outF,
    const unsigned short* __restrict__ eidx, const int* __restrict__ off,
    int n)
{
    __shared__ hh2 Xs[64 * 66];
    __shared__ hh2 Ws[64 * 66];
    cg::grid_group grid = cg::this_grid();
    int t = threadIdx.x;

    // ---- phase 1: z = fp16( dis * (X @ W^T) ), grid-stride over 64-node tiles
    int ntiles = (n + 63) >> 6;
    for (int tile = blockIdx.x; tile < ntiles; tile += gridDim.x) {
        int m0 = tile * 64;
#pragma unroll
        for (int r = 0; r < 8; ++r) {               // stage W: 64x128 fp32 -> half2
            int f = t + 256 * r;
            int o = f >> 5, kq = f & 31;
            float4 w = ((const float4*)W)[f];
            Ws[o * 66 + kq * 2]     = hh2{(_Float16)w.x, (_Float16)w.y};
            Ws[o * 66 + kq * 2 + 1] = hh2{(_Float16)w.z, (_Float16)w.w};
        }
#pragma unroll
        for (int r = 0; r < 8; ++r) {               // stage X tile (clamped tail)
            int f = t + 256 * r;
            int node = f >> 5, kq = f & 31;
            int gv = min(m0 + node, n - 1);
            float4 xv = ((const float4*)(x + (size_t)gv * IN_CH))[kq];
            Xs[node * 66 + kq * 2]     = hh2{(_Float16)xv.x, (_Float16)xv.y};
            Xs[node * 66 + kq * 2 + 1] = hh2{(_Float16)xv.z, (_Float16)xv.w};
        }
        __syncthreads();
        int tx = t & 15, ty = t >> 4;
        float acc[4][4];
#pragma unroll
        for (int i = 0; i < 4; ++i)
#pragma unroll
            for (int j = 0; j < 4; ++j) acc[i][j] = 0.f;
#pragma unroll 4
        for (int kq = 0; kq < 32; ++kq) {           // 4 k-values per step
            hh2 xa0[4], xa1[4], wb0[4], wb1[4];
#pragma unroll
            for (int i = 0; i < 4; ++i) {
                int base = (tx + 16 * i) * 66 + kq * 2;
                xa0[i] = Xs[base]; xa1[i] = Xs[base + 1];
            }
#pragma unroll
            for (int j = 0; j < 4; ++j) {
                int base = (ty * 4 + j) * 66 + kq * 2;
                wb0[j] = Ws[base]; wb1[j] = Ws[base + 1];
            }
#pragma unroll
            for (int i = 0; i < 4; ++i)
#pragma unroll
                for (int j = 0; j < 4; ++j) {
                    float s = acc[i][j];
                    s = __builtin_amdgcn_fdot2(xa0[i], wb0[j], s, false);
                    s = __builtin_amdgcn_fdot2(xa1[i], wb1[j], s, false);
                    acc[i][j] = s;
                }
        }
#pragma unroll
        for (int i = 0; i < 4; ++i) {
            int v = m0 + tx + 16 * i;
            if (v < n) {
                float dv = dis[v];
                union { __half2 h[2]; float2 f; } u;
                u.h[0] = __floats2half2_rn(dv * acc[i][0], dv * acc[i][1]);
                u.h[1] = __floats2half2_rn(dv * acc[i][2], dv * acc[i][3]);
                *(float2*)&zA[(size_t)v * OUT_CH + ty * 4] = u.f;   // 8B aligned
            }
        }
        __syncthreads();   // safe restage if a block ever gets a 2nd tile
    }
    grid.sync();

    // ---- phase 2: hop MODE 0 (zA -> zB), wave per node, grid-stride ----
    int waveId = (int)((blockIdx.x * 256 + t) >> 6);
    int nwaves = (int)((gridDim.x * 256) >> 6);
    int lane = t & 63;
    for (int v = waveId; v < n; v += nwaves)
        hop_node<0>(v, lane, zA, (void*)zB, eidx, off, dis, nullptr);
    grid.sync();

    // ---- phase 3: hop MODE 1 (zB -> outF) ----
    for (int v = waveId; v < n; v += nwaves)
        hop_node<1>(v, lane, zB, (void*)outF, eidx, off, dis, bias);
}

// ============================================================================
// Fallback (non-cooperative) kernels — verified round-1 path
// ============================================================================
__global__ void __launch_bounds__(512) histo_kernel(const int* __restrict__ col,
                                                    int* __restrict__ blkcnt,
                                                    int E, int chunk) {
    __shared__ int h[256];
    int blk = blockIdx.x, tid = threadIdx.x;
    if (tid < 256) h[tid] = 0;
    __syncthreads();
    int s = blk * chunk, e = min(s + chunk, E);
    for (int i = s + tid; i < e; i += 512)
        atomicAdd(&h[col[i] >> 8], 1);
    __syncthreads();
    if (tid < 256) blkcnt[blk * 256 + tid] = h[tid];
}

__global__ void __launch_bounds__(256) scanblk_kernel(int* __restrict__ blkcnt,
                                                      int* __restrict__ totals) {
    __shared__ int ps[256];
    int b = blockIdx.x, tid = threadIdx.x;
    int i0 = (2 * tid) * 256 + b, i1 = (2 * tid + 1) * 256 + b;
    int a0 = blkcnt[i0], a1 = blkcnt[i1];
    int lsum = a0 + a1;
    ps[tid] = lsum;
    __syncthreads();
    for (int d = 1; d < 256; d <<= 1) {
        int t = 0;
        if (tid >= d) t = ps[tid - d];
        __syncthreads();
        if (tid >= d) ps[tid] += t;
        __syncthreads();
    }
    int excl = ps[tid] - lsum;
    blkcnt[i0] = excl;
    blkcnt[i1] = excl + a0;
    if (tid == 255) totals[b] = excl + lsum;
}

__global__ void __launch_bounds__(512) bucket_scatter_kernel(const int* __restrict__ row,
                                                             const int* __restrict__ col,
                                                             const int* __restrict__ blkcnt,
                                                             const int* __restrict__ totals,
                                                             unsigned int* __restrict__ tmp,
                                                             int E, int chunk, int nbkt) {
    __shared__ int ps[256];
    __shared__ int cur[256];
    int blk = blockIdx.x, tid = threadIdx.x;
    int v = 0;
    if (tid < 256) { v = (tid < nbkt) ? totals[tid] : 0; ps[tid] = v; }
    __syncthreads();
    for (int d = 1; d < 256; d <<= 1) {
        int t = 0;
        if (tid < 256 && tid >= d) t = ps[tid - d];
        __syncthreads();
        if (tid < 256 && tid >= d) ps[tid] += t;
        __syncthreads();
    }
    if (tid < 256) cur[tid] = (ps[tid] - v) + blkcnt[blk * 256 + tid];
    __syncthreads();
    int s = blk * chunk, e = min(s + chunk, E);
    for (int i = s + tid; i < e; i += 512) {
        int c = col[i], r = row[i];
        int p = atomicAdd(&cur[c >> 8], 1);
        tmp[p] = ((unsigned)(c & 255) << 16) | (unsigned)r;
    }
}

__global__ void __launch_bounds__(512) bucket_sort_kernel(const unsigned int* __restrict__ tmp,
                                                          const int* __restrict__ totals,
                                                          int* __restrict__ off,
                                                          float* __restrict__ dis,
                                                          unsigned short* __restrict__ eidx,
                                                          int nbkt, int E, int n) {
    __shared__ int bs[256];
    __shared__ int cntl[256];
    __shared__ int sc[256];
    __shared__ int posl[256];
    int b = blockIdx.x, tid = threadIdx.x;
    int v = 0;
    if (tid < 256) { v = (tid < nbkt) ? totals[tid] : 0; bs[tid] = v; }
    __syncthreads();
    for (int d = 1; d < 256; d <<= 1) {
        int t = 0;
        if (tid < 256 && tid >= d) t = bs[tid - d];
        __syncthreads();
        if (tid < 256 && tid >= d) bs[tid] += t;
        __syncthreads();
    }
    if (tid < 256) bs[tid] -= v;
    if (tid < 256) cntl[tid] = 0;
    __syncthreads();
    int s = bs[b];
    int e = s + ((b < nbkt) ? totals[b] : 0);
    for (int i = s + tid; i < e; i += 512)
        atomicAdd(&cntl[tmp[i] >> 16], 1);
    __syncthreads();
    int c = 0;
    if (tid < 256) { c = cntl[tid]; sc[tid] = c; }
    __syncthreads();
    for (int d = 1; d < 256; d <<= 1) {
        int t = 0;
        if (tid < 256 && tid >= d) t = sc[tid - d];
        __syncthreads();
        if (tid < 256 && tid >= d) sc[tid] += t;
        __syncthreads();
    }
    if (tid < 256) {
        int excl = sc[tid] - c;
        int gid = (b << 8) + tid;
        if (gid < n) {
            off[gid] = s + excl;
            dis[gid] = rsqrtf((float)(c + 1));
        }
        posl[tid] = s + excl;
    }
    if (b == 0 && tid == 0) off[n] = E;
    __syncthreads();
    for (int i = s + tid; i < e; i += 512) {
        unsigned int w = tmp[i];
        int p = atomicAdd(&posl[w >> 16], 1);
        eidx[p] = (unsigned short)(w & 0xFFFFu);
    }
}

__global__ void __launch_bounds__(256) gemm_kernel(const float* __restrict__ x,
                                                   const float* __restrict__ W,
                                                   const float* __restrict__ dis,
                                                   __half* __restrict__ z, int n) {
    __shared__ hh2 Xs[64 * 66];
    __shared__ hh2 Ws[64 * 66];
    int t = threadIdx.x;
    int m0 = blockIdx.x * 64;
#pragma unroll
    for (int r = 0; r < 8; ++r) {
        int f = t + 256 * r;
        int o = f >> 5, kq = f & 31;
        float4 w = ((const float4*)W)[f];
        Ws[o * 66 + kq * 2]     = hh2{(_Float16)w.x, (_Float16)w.y};
        Ws[o * 66 + kq * 2 + 1] = hh2{(_Float16)w.z, (_Float16)w.w};
    }
#pragma unroll
    for (int r = 0; r < 8; ++r) {
        int f = t + 256 * r;
        int node = f >> 5, kq = f & 31;
        int gv = min(m0 + node, n - 1);
        float4 xv = ((const float4*)(x + (size_t)gv * IN_CH))[kq];
        Xs[node * 66 + kq * 2]     = hh2{(_Float16)xv.x, (_Float16)xv.y};
        Xs[node * 66 + kq * 2 + 1] = hh2{(_Float16)xv.z, (_Float16)xv.w};
    }
    __syncthreads();
    int tx = t & 15, ty = t >> 4;
    float acc[4][4];
#pragma unroll
    for (int i = 0; i < 4; ++i)
#pragma unroll
        for (int j = 0; j < 4; ++j) acc[i][j] = 0.f;
#pragma unroll 4
    for (int kq = 0; kq < 32; ++kq) {
        hh2 xa0[4], xa1[4], wb0[4], wb1[4];
#pragma unroll
        for (int i = 0; i < 4; ++i) {
            int base = (tx + 16 * i) * 66 + kq * 2;
            xa0[i] = Xs[base]; xa1[i] = Xs[base + 1];
        }
#pragma unroll
        for (int j = 0; j < 4; ++j) {
            int base = (ty * 4 + j) * 66 + kq * 2;
            wb0[j] = Ws[base]; wb1[j] = Ws[base + 1];
        }
#pragma unroll
        for (int i = 0; i < 4; ++i)
#pragma unroll
            for (int j = 0; j < 4; ++j) {
                float s = acc[i][j];
                s = __builtin_amdgcn_fdot2(xa0[i], wb0[j], s, false);
                s = __builtin_amdgcn_fdot2(xa1[i], wb1[j], s, false);
                acc[i][j] = s;
            }
    }
#pragma unroll
    for (int i = 0; i < 4; ++i) {
        int v = m0 + tx + 16 * i;
        if (v < n) {
            float dv = dis[v];
            union { __half2 h[2]; float2 f; } u;
            u.h[0] = __floats2half2_rn(dv * acc[i][0], dv * acc[i][1]);
            u.h[1] = __floats2half2_rn(dv * acc[i][2], dv * acc[i][3]);
            *(float2*)&z[(size_t)v * OUT_CH + ty * 4] = u.f;
        }
    }
}

template <int MODE>
__global__ void __launch_bounds__(256) hop_kernel(const __half* __restrict__ zin,
                                                  void* __restrict__ out,
                                                  const unsigned short* __restrict__ eidx,
                                                  const int* __restrict__ off,
                                                  const float* __restrict__ dis,
                                                  const float* __restrict__ bias, int n) {
    int v = (int)((blockIdx.x * 256 + threadIdx.x) >> 6);
    if (v >= n) return;
    hop_node<MODE>(v, threadIdx.x & 63, zin, out, eidx, off, dis, bias);
}

// ============================================================================
extern "C" void kernel_launch(void* const* d_in, const int* in_sizes, int n_in,
                              void* d_out, int out_size, void* d_ws, size_t ws_size,
                              hipStream_t stream) {
    const float* x = (const float*)d_in[0];
    const int* ei = (const int*)d_in[1];
    const float* W = (const float*)d_in[2];
    const float* b = (const float*)d_in[3];
    int n = in_sizes[0] / IN_CH;   // 50000
    int E = in_sizes[1] / 2;       // 800000
    const int* row = ei;           // edge_index[0] = source
    const int* col = ei + E;       // edge_index[1] = target

    char* ws = (char*)d_ws;
    size_t o = 0;
    auto alloc = [&](size_t bytes) -> void* {
        void* p = ws + o;
        o += (bytes + 255) & ~(size_t)255;
        return p;
    };
    int nbkt = (n + 255) >> 8;      // 196
    int chunk = (E + NB - 1) / NB;  // 1563

    int*            blkcnt = (int*)alloc((size_t)NB * 256 * 4);
    int*            totals = (int*)alloc(256 * 4);
    unsigned int*   tmp    = (unsigned int*)alloc((size_t)E * 4);
    int*            off    = (int*)alloc((size_t)(n + 1) * 4);
    float*          dis    = (float*)alloc((size_t)n * 4);
    unsigned short* eidx   = (unsigned short*)alloc((size_t)E * 2);
    __half*         zA     = (__half*)alloc((size_t)n * OUT_CH * 2);
    __half*         zB     = (__half*)alloc((size_t)n * OUT_CH * 2);
    float*          outF   = (float*)d_out;

    // ---- stage 1: preprocessing (cooperative, with fallback) ----
    {
        void* pargs[] = {(void*)&row, (void*)&col, (void*)&blkcnt, (void*)&totals,
                         (void*)&tmp, (void*)&off, (void*)&dis, (void*)&eidx,
                         (void*)&E, (void*)&n, (void*)&chunk, (void*)&nbkt};
        hipError_t err = hipLaunchCooperativeKernel((const void*)pre_kernel,
                                                    dim3(NB), dim3(512), pargs, 0, stream);
        if (err != hipSuccess) {
            (void)hipGetLastError();
            histo_kernel<<<NB, 512, 0, stream>>>(col, blkcnt, E, chunk);
            scanblk_kernel<<<nbkt, 256, 0, stream>>>(blkcnt, totals);
            bucket_scatter_kernel<<<NB, 512, 0, stream>>>(row, col, blkcnt, totals, tmp, E, chunk, nbkt);
            bucket_sort_kernel<<<nbkt, 512, 0, stream>>>(tmp, totals, off, dis, eidx, nbkt, E, n);
        }
    }

    // ---- stage 2: gemm + 2 hops (cooperative, with fallback) ----
    {
        void* cargs[] = {(void*)&x, (void*)&W, (void*)&dis, (void*)&b,
                         (void*)&zA, (void*)&zB, (void*)&outF,
                         (void*)&eidx, (void*)&off, (void*)&n};
        hipError_t err = hipLaunchCooperativeKernel((const void*)compute_kernel,
                                                    dim3(CB), dim3(256), cargs, 0, stream);
        if (err != hipSuccess) {
            (void)hipGetLastError();
            gemm_kernel<<<(n + 63) / 64, 256, 0, stream>>>(x, W, dis, zA, n);
            int hopBlocks = (n + 3) / 4;
            hop_kernel<0><<<hopBlocks, 256, 0, stream>>>(zA, (void*)zB, eidx, off, dis, nullptr, n);
            hop_kernel<1><<<hopBlocks, 256, 0, stream>>>(zB, (void*)outF, eidx, off, dis, b, n);
        }
    }
}

// Round 3
// 153.717 us; speedup vs baseline: 3.8189x; 3.8189x over previous
//
#include <hip/hip_runtime.h>
#include <hip/hip_bf16.h>
#include <hip/hip_fp16.h>

#define IN_CH 128
#define OUT_CH 64
#define NB 256          // edge-chunk blocks for histo/bucket_scatter (1 block/CU)
#define CHUNK_CAP 3200  // LDS staging capacity in bucket_scatter (chunk = 3125)
#define SORT_CAP 6144   // LDS staging capacity in bucket_sort (mean bucket = 4096)

typedef _Float16 hh2 __attribute__((ext_vector_type(2)));   // native half2 for v_dot2

// ---------------- K1: per-block 256-bucket histogram of col>>8 ----------------
// Writes blkcnt (consumed/overwritten by scan) AND rawcnt (preserved raw counts).
__global__ void __launch_bounds__(512) histo_kernel(const int* __restrict__ col,
                                                    int* __restrict__ blkcnt,
                                                    int* __restrict__ rawcnt,
                                                    int E, int chunk) {
    __shared__ int h[256];
    int blk = blockIdx.x, tid = threadIdx.x;
    if (tid < 256) h[tid] = 0;
    __syncthreads();
    int s = blk * chunk, e = min(s + chunk, E);
    for (int i = s + tid; i < e; i += 512)
        atomicAdd(&h[col[i] >> 8], 1);          // LDS atomic
    __syncthreads();
    if (tid < 256) {
        blkcnt[blk * 256 + tid] = h[tid];       // coalesced
        rawcnt[blk * 256 + tid] = h[tid];
    }
}

// ---------------- K2: per-bucket exclusive scan over NB block-counts (in place) ----------------
// One block per bucket; 256 threads, one value each (NB == 256).
__global__ void __launch_bounds__(256) scanblk_kernel(int* __restrict__ blkcnt,
                                                      int* __restrict__ totals) {
    __shared__ int ps[256];
    int b = blockIdx.x, tid = threadIdx.x;
    int i0 = tid * 256 + b;
    int a0 = blkcnt[i0];
    ps[tid] = a0;
    __syncthreads();
    for (int d = 1; d < 256; d <<= 1) {
        int t = 0;
        if (tid >= d) t = ps[tid - d];
        __syncthreads();
        if (tid >= d) ps[tid] += t;
        __syncthreads();
    }
    blkcnt[i0] = ps[tid] - a0;                  // exclusive within-bucket offset
    if (tid == 255) totals[b] = ps[255];
}

// ---------------- K3: scatter edges into bucket-contiguous tmp ----------------
// LDS-staged local counting sort: writes become ~12-entry contiguous runs
// instead of isolated 4B stores (write-amp ~16x -> ~1.5x).
__global__ void __launch_bounds__(512) bucket_scatter_kernel(const int* __restrict__ row,
                                                             const int* __restrict__ col,
                                                             const int* __restrict__ blkcnt,
                                                             const int* __restrict__ rawcnt,
                                                             const int* __restrict__ totals,
                                                             unsigned int* __restrict__ tmp,
                                                             int E, int chunk, int nbkt) {
    __shared__ int ps[256];      // scan of totals -> bucket bases
    __shared__ int ls[256];      // scan of this block's raw counts
    __shared__ int bias[256];    // dest = bias[k] + local_pos
    __shared__ int curl[256];    // local cursor (starts at loff)
    __shared__ unsigned int vall[CHUNK_CAP];
    __shared__ int destl[CHUNK_CAP];
    int blk = blockIdx.x, tid = threadIdx.x;
    int t0 = 0, lr = 0;
    if (tid < 256) {
        t0 = (tid < nbkt) ? totals[tid] : 0;
        ps[tid] = t0;
        lr = rawcnt[blk * 256 + tid];
        ls[tid] = lr;
    }
    __syncthreads();
    for (int d = 1; d < 256; d <<= 1) {         // two inclusive scans in lockstep
        int t = 0, u = 0;
        if (tid < 256 && tid >= d) { t = ps[tid - d]; u = ls[tid - d]; }
        __syncthreads();
        if (tid < 256 && tid >= d) { ps[tid] += t; ls[tid] += u; }
        __syncthreads();
    }
    if (tid < 256) {
        int bucket_base = ps[tid] - t0;                     // exclusive bucket base in tmp
        int loff = ls[tid] - lr;                            // local exclusive offset
        bias[tid] = bucket_base + blkcnt[blk * 256 + tid] - loff;
        curl[tid] = loff;
    }
    __syncthreads();
    int s = blk * chunk, e = min(s + chunk, E);
    int csize = e - s;
    if (csize <= CHUNK_CAP) {
        for (int i = s + tid; i < e; i += 512) {
            int c = col[i], r = row[i];
            int k = c >> 8;
            int p = atomicAdd(&curl[k], 1);                 // LDS atomic, local pos
            vall[p]  = ((unsigned)(c & 255) << 16) | (unsigned)r;
            destl[p] = bias[k] + p;
        }
        __syncthreads();
        for (int j = tid; j < csize; j += 512)              // run-coalesced global writes
            tmp[destl[j]] = vall[j];
    } else {                                                // safety fallback: direct scatter
        for (int i = s + tid; i < e; i += 512) {
            int c = col[i], r = row[i];
            int k = c >> 8;
            int p = atomicAdd(&curl[k], 1);
            tmp[bias[k] + p] = ((unsigned)(c & 255) << 16) | (unsigned)r;
        }
    }
}

// ---------------- K4: per-bucket counting sort -> off/dis/eidx ----------------
// eidx scattered into LDS then written coalesced (2B global scatter eliminated).
__global__ void __launch_bounds__(512) bucket_sort_kernel(const unsigned int* __restrict__ tmp,
                                                          const int* __restrict__ totals,
                                                          int* __restrict__ off,
                                                          float* __restrict__ dis,
                                                          unsigned short* __restrict__ eidx,
                                                          int nbkt, int E, int n) {
    __shared__ int bs[256];
    __shared__ int cntl[256];
    __shared__ int sc[256];
    __shared__ int posr[256];           // RELATIVE running cursor
    __shared__ unsigned short el[SORT_CAP];
    int b = blockIdx.x, tid = threadIdx.x;
    int v = 0;
    if (tid < 256) { v = (tid < nbkt) ? totals[tid] : 0; bs[tid] = v; }
    __syncthreads();
    for (int d = 1; d < 256; d <<= 1) {
        int t = 0;
        if (tid < 256 && tid >= d) t = bs[tid - d];
        __syncthreads();
        if (tid < 256 && tid >= d) bs[tid] += t;
        __syncthreads();
    }
    if (tid < 256) bs[tid] -= v;                 // exclusive bucket bases
    if (tid < 256) cntl[tid] = 0;
    __syncthreads();
    int s = bs[b];
    int cnt = (b < nbkt) ? totals[b] : 0;
    int e = s + cnt;
    for (int i = s + tid; i < e; i += 512)
        atomicAdd(&cntl[tmp[i] >> 16], 1);       // LDS atomic
    __syncthreads();
    int c = 0;
    if (tid < 256) { c = cntl[tid]; sc[tid] = c; }
    __syncthreads();
    for (int d = 1; d < 256; d <<= 1) {
        int t = 0;
        if (tid < 256 && tid >= d) t = sc[tid - d];
        __syncthreads();
        if (tid < 256 && tid >= d) sc[tid] += t;
        __syncthreads();
    }
    if (tid < 256) {
        int excl = sc[tid] - c;
        int gid = (b << 8) + tid;
        if (gid < n) {
            off[gid] = s + excl;
            dis[gid] = rsqrtf((float)(c + 1));   // +1 self-loop (gcn_norm)
        }
        posr[tid] = excl;                        // relative cursor
    }
    if (b == 0 && tid == 0) off[n] = E;
    __syncthreads();
    bool staged = (cnt <= SORT_CAP);             // block-uniform
    if (staged) {
        for (int i = s + tid; i < e; i += 512) {
            unsigned int w = tmp[i];
            int p = atomicAdd(&posr[w >> 16], 1);
            el[p] = (unsigned short)(w & 0xFFFFu);   // LDS scatter
        }
        __syncthreads();
        for (int i = tid; i < cnt; i += 512)         // coalesced global write
            eidx[s + i] = el[i];
    } else {                                         // safety fallback (never at this size)
        for (int i = s + tid; i < e; i += 512) {
            unsigned int w = tmp[i];
            int p = atomicAdd(&posr[w >> 16], 1);
            eidx[s + p] = (unsigned short)(w & 0xFFFFu);
        }
    }
}

// ---------------- z = fp16( dis * (X @ W^T) ) : half2 LDS + v_dot2_f32_f16 ----------------
__global__ void __launch_bounds__(256) gemm_kernel(const float* __restrict__ x,
                                                   const float* __restrict__ W,
                                                   const float* __restrict__ dis,
                                                   __half* __restrict__ z, int n) {
    __shared__ hh2 Xs[64 * 66];
    __shared__ hh2 Ws[64 * 66];
    int t = threadIdx.x;
    int m0 = blockIdx.x * 64;
#pragma unroll
    for (int r = 0; r < 8; ++r) {               // stage W: 64x128 fp32 -> half2
        int f = t + 256 * r;                    // float4 index; row=f>>5, kq=f&31
        int o = f >> 5, kq = f & 31;
        float4 w = ((const float4*)W)[f];
        Ws[o * 66 + kq * 2]     = hh2{(_Float16)w.x, (_Float16)w.y};
        Ws[o * 66 + kq * 2 + 1] = hh2{(_Float16)w.z, (_Float16)w.w};
    }
#pragma unroll
    for (int r = 0; r < 8; ++r) {               // stage X tile (clamped tail)
        int f = t + 256 * r;
        int node = f >> 5, kq = f & 31;
        int gv = min(m0 + node, n - 1);
        float4 xv = ((const float4*)(x + (size_t)gv * IN_CH))[kq];
        Xs[node * 66 + kq * 2]     = hh2{(_Float16)xv.x, (_Float16)xv.y};
        Xs[node * 66 + kq * 2 + 1] = hh2{(_Float16)xv.z, (_Float16)xv.w};
    }
    __syncthreads();
    int tx = t & 15, ty = t >> 4;
    float acc[4][4];
#pragma unroll
    for (int i = 0; i < 4; ++i)
#pragma unroll
        for (int j = 0; j < 4; ++j) acc[i][j] = 0.f;

#pragma unroll 4
    for (int kq = 0; kq < 32; ++kq) {           // 4 k-values per step
        hh2 xa0[4], xa1[4], wb0[4], wb1[4];
#pragma unroll
        for (int i = 0; i < 4; ++i) {
            int base = (tx + 16 * i) * 66 + kq * 2;
            xa0[i] = Xs[base]; xa1[i] = Xs[base + 1];
        }
#pragma unroll
        for (int j = 0; j < 4; ++j) {
            int base = (ty * 4 + j) * 66 + kq * 2;
            wb0[j] = Ws[base]; wb1[j] = Ws[base + 1];
        }
#pragma unroll
        for (int i = 0; i < 4; ++i)
#pragma unroll
            for (int j = 0; j < 4; ++j) {
                float s = acc[i][j];
                s = __builtin_amdgcn_fdot2(xa0[i], wb0[j], s, false);
                s = __builtin_amdgcn_fdot2(xa1[i], wb1[j], s, false);
                acc[i][j] = s;
            }
    }
#pragma unroll
    for (int i = 0; i < 4; ++i) {
        int v = m0 + tx + 16 * i;
        if (v < n) {
            float dv = dis[v];
            union { __half2 h[2]; float2 f; } u;
            u.h[0] = __floats2half2_rn(dv * acc[i][0], dv * acc[i][1]);
            u.h[1] = __floats2half2_rn(dv * acc[i][2], dv * acc[i][3]);
            *(float2*)&z[(size_t)v * OUT_CH + ty * 4] = u.f;   // 8B aligned
        }
    }
}

// ---------------- propagation hop: wave per node, FOUR 8-edge gather batches in flight ----------------
// t[v] = zin[v] + sum_{edges} zin[row]; rows are 64 halves = 128B.
// 32 edges covered in ONE pass (P[deg>32] ~ 1e-4 for Poisson(16)); rare fallback loop.
// MODE 0: out(half) = dis^2 * t (next z);  MODE 1: out(float) = dis * t + bias.
#define ACC8(raw) { const __half2* h2_ = (const __half2*)&(raw);              \
    float2 f0_ = __half22float2(h2_[0]), f1_ = __half22float2(h2_[1]);        \
    float2 f2_ = __half22float2(h2_[2]), f3_ = __half22float2(h2_[3]);        \
    a0 += f0_.x; a1 += f0_.y; a2 += f1_.x; a3 += f1_.y;                       \
    a4 += f2_.x; a5 += f2_.y; a6 += f3_.x; a7 += f3_.y; }

template <int MODE>
__global__ void __launch_bounds__(256) hop_kernel(const __half* __restrict__ zin,
                                                  void* __restrict__ out,
                                                  const unsigned short* __restrict__ eidx,
                                                  const int* __restrict__ off,
                                                  const float* __restrict__ dis,
                                                  const float* __restrict__ bias, int n) {
    int v = (int)((blockIdx.x * 256 + threadIdx.x) >> 6);
    if (v >= n) return;
    int lane = threadIdx.x & 63;
    int grp = lane >> 3;       // edge slot in the octet
    int sub = lane & 7;        // 16B chunk of the 128B row
    int s = off[v], e = off[v + 1];
    float dv = dis[v];         // hoisted: overlaps with gather latency
    float a0 = 0.f, a1 = 0.f, a2 = 0.f, a3 = 0.f;
    float a4 = 0.f, a5 = 0.f, a6 = 0.f, a7 = 0.f;
    if (grp == 0) {            // self-loop term (z already carries dis scaling)
        float4 raw = ((const float4*)(zin + (size_t)v * OUT_CH))[sub];
        ACC8(raw);
    }
    // ---- 32 edges in flight: 4 independent predicated batches ----
    int i0 = s + grp;
    int i1 = i0 + 8, i2 = i0 + 16, i3 = i0 + 24;
    bool h0 = i0 < e, h1 = i1 < e, h2 = i2 < e, h3 = i3 < e;
    int r0 = h0 ? (int)eidx[i0] : 0;
    int r1 = h1 ? (int)eidx[i1] : 0;
    int r2 = h2 ? (int)eidx[i2] : 0;
    int r3 = h3 ? (int)eidx[i3] : 0;
    float4 rA = make_float4(0.f, 0.f, 0.f, 0.f);
    float4 rB = make_float4(0.f, 0.f, 0.f, 0.f);
    float4 rC = make_float4(0.f, 0.f, 0.f, 0.f);
    float4 rD = make_float4(0.f, 0.f, 0.f, 0.f);
    if (h0) rA = ((const float4*)(zin + (size_t)r0 * OUT_CH))[sub];
    if (h1) rB = ((const float4*)(zin + (size_t)r1 * OUT_CH))[sub];
    if (h2) rC = ((const float4*)(zin + (size_t)r2 * OUT_CH))[sub];
    if (h3) rD = ((const float4*)(zin + (size_t)r3 * OUT_CH))[sub];
    ACC8(rA); ACC8(rB); ACC8(rC); ACC8(rD);
    if (e - s > 32) {          // rare (deg > 32): pipelined 2-batch loop
        int j0 = s + 32 + grp, j1 = j0 + 8;
        bool g0 = j0 < e, g1 = j1 < e;
        int q0 = g0 ? (int)eidx[j0] : 0;
        int q1 = g1 ? (int)eidx[j1] : 0;
        while (g0) {           // g1 implies g0
            int k0 = j0 + 16, k1 = j1 + 16;
            bool f0 = k0 < e, f1 = k1 < e;
            int p0 = f0 ? (int)eidx[k0] : 0;   // prefetch next descriptors
            int p1 = f1 ? (int)eidx[k1] : 0;
            float4 xA = make_float4(0.f, 0.f, 0.f, 0.f);
            float4 xB = make_float4(0.f, 0.f, 0.f, 0.f);
            if (g0) xA = ((const float4*)(zin + (size_t)q0 * OUT_CH))[sub];
            if (g1) xB = ((const float4*)(zin + (size_t)q1 * OUT_CH))[sub];
            ACC8(xA); ACC8(xB);
            j0 = k0; j1 = k1; q0 = p0; q1 = p1; g0 = f0; g1 = f1;
        }
    }
    // reduce the 8 edge slots (lanes differing in bits 3..5)
#pragma unroll
    for (int m = 8; m <= 32; m <<= 1) {
        a0 += __shfl_xor(a0, m, 64); a1 += __shfl_xor(a1, m, 64);
        a2 += __shfl_xor(a2, m, 64); a3 += __shfl_xor(a3, m, 64);
        a4 += __shfl_xor(a4, m, 64); a5 += __shfl_xor(a5, m, 64);
        a6 += __shfl_xor(a6, m, 64); a7 += __shfl_xor(a7, m, 64);
    }
    if (grp == 0) {
        if (MODE == 0) {
            float sc = dv * dv;
            union { __half2 h[4]; float4 f; } u;
            u.h[0] = __floats2half2_rn(sc * a0, sc * a1);
            u.h[1] = __floats2half2_rn(sc * a2, sc * a3);
            u.h[2] = __floats2half2_rn(sc * a4, sc * a5);
            u.h[3] = __floats2half2_rn(sc * a6, sc * a7);
            ((float4*)((__half*)out + (size_t)v * OUT_CH))[sub] = u.f;
        } else {
            const float4* bp = (const float4*)(bias + sub * 8);
            float4 b0 = bp[0], b1 = bp[1];
            float* op = (float*)out + (size_t)v * OUT_CH + sub * 8;
            *(float4*)op = make_float4(fmaf(dv, a0, b0.x), fmaf(dv, a1, b0.y),
                                       fmaf(dv, a2, b0.z), fmaf(dv, a3, b0.w));
            *(float4*)(op + 4) = make_float4(fmaf(dv, a4, b1.x), fmaf(dv, a5, b1.y),
                                             fmaf(dv, a6, b1.z), fmaf(dv, a7, b1.w));
        }
    }
}

extern "C" void kernel_launch(void* const* d_in, const int* in_sizes, int n_in,
                              void* d_out, int out_size, void* d_ws, size_t ws_size,
                              hipStream_t stream) {
    const float* x = (const float*)d_in[0];
    const int* ei = (const int*)d_in[1];
    const float* W = (const float*)d_in[2];
    const float* b = (const float*)d_in[3];
    int n = in_sizes[0] / IN_CH;   // 50000
    int E = in_sizes[1] / 2;       // 800000
    const int* row = ei;           // edge_index[0] = source
    const int* col = ei + E;       // edge_index[1] = target

    char* ws = (char*)d_ws;
    size_t o = 0;
    auto alloc = [&](size_t bytes) -> void* {
        void* p = ws + o;
        o += (bytes + 255) & ~(size_t)255;
        return p;
    };
    int nbkt = (n + 255) >> 8;      // 196
    int chunk = (E + NB - 1) / NB;  // 3125

    int*            blkcnt = (int*)alloc((size_t)NB * 256 * 4);
    int*            rawcnt = (int*)alloc((size_t)NB * 256 * 4);
    int*            totals = (int*)alloc(256 * 4);
    unsigned int*   tmp    = (unsigned int*)alloc((size_t)E * 4);
    int*            off    = (int*)alloc((size_t)(n + 1) * 4);
    float*          dis    = (float*)alloc((size_t)n * 4);
    unsigned short* eidx   = (unsigned short*)alloc((size_t)E * 2);
    __half*         zA     = (__half*)alloc((size_t)n * OUT_CH * 2);
    __half*         zB     = (__half*)alloc((size_t)n * OUT_CH * 2);

    histo_kernel<<<NB, 512, 0, stream>>>(col, blkcnt, rawcnt, E, chunk);
    scanblk_kernel<<<nbkt, 256, 0, stream>>>(blkcnt, totals);
    bucket_scatter_kernel<<<NB, 512, 0, stream>>>(row, col, blkcnt, rawcnt, totals, tmp, E, chunk, nbkt);
    bucket_sort_kernel<<<nbkt, 512, 0, stream>>>(tmp, totals, off, dis, eidx, nbkt, E, n);
    gemm_kernel<<<(n + 63) / 64, 256, 0, stream>>>(x, W, dis, zA, n);
    int hopBlocks = (n + 3) / 4;   // wave per node
    hop_kernel<0><<<hopBlocks, 256, 0, stream>>>(zA, zB, eidx, off, dis, nullptr, n);
    hop_kernel<1><<<hopBlocks, 256, 0, stream>>>(zB, d_out, eidx, off, dis, b, n);
}